// Round 1
// baseline (1024.050 us; speedup 1.0000x reference)
//
#include <hip/hip_runtime.h>

#define D  256
#define BM 64
#define BN 256
#define BK 32

// ---------------- kernel 1: codebook squared norms -> ws ----------------
__global__ void vq_c2_kernel(const float* __restrict__ cb, float* __restrict__ c2) {
    const int row  = blockIdx.x;
    const int lane = threadIdx.x;  // 64 threads = 1 wave
    const float4 v = *reinterpret_cast<const float4*>(cb + (size_t)row * D + lane * 4);
    float s = v.x * v.x + v.y * v.y + v.z * v.z + v.w * v.w;
    #pragma unroll
    for (int off = 32; off > 0; off >>= 1) s += __shfl_down(s, off, 64);
    if (lane == 0) c2[row] = s;
}

// ---------------- kernel 2: fused GEMM + argmin ----------------
// block: 256 threads, owns BM=64 rows, iterates all N codes.
// thread micro-tile: 8 rows x 8 cols. tx in [0,32) along n, ty in [0,8) along m.
// score s = c2[n] - 2*dot(x,c); argmin(s) == argmin ||x-c||^2.
__global__ __launch_bounds__(256, 2) void vq_argmin_kernel(
        const float* __restrict__ x, const float* __restrict__ cb,
        const float* __restrict__ c2, float* __restrict__ idx_out, int N) {
    __shared__ float xs[BK * BM];   // xT[k][m], 8 KB, restaged per k-chunk
    __shared__ float cs[BK * BN];   // cT[k][n], 32 KB, restaged per (n,k)-chunk

    const int tid = threadIdx.x;
    const int tx  = tid & 31;
    const int ty  = tid >> 5;
    const int m0  = blockIdx.x * BM;
    const float* xg = x + (size_t)m0 * D;

    float runmin[8];
    int   runidx[8];
    #pragma unroll
    for (int i = 0; i < 8; ++i) { runmin[i] = 3.4e38f; runidx[i] = 0; }

    float acc[8][8];
    #pragma unroll
    for (int i = 0; i < 8; ++i)
        #pragma unroll
        for (int j = 0; j < 8; ++j) acc[i][j] = 0.0f;

    for (int nc = 0; nc < N; nc += BN) {
        for (int kc = 0; kc < D; kc += BK) {
            __syncthreads();
            // stage xT chunk: 2048 floats. 8 lanes cover one row's 32 k-values.
            #pragma unroll
            for (int q = 0; q < 2; ++q) {
                const int m  = q * 32 + (tid >> 3);
                const int kl = (tid & 7) * 4;
                const float4 v = *reinterpret_cast<const float4*>(xg + (size_t)m * D + kc + kl);
                xs[(kl + 0) * BM + m] = v.x;
                xs[(kl + 1) * BM + m] = v.y;
                xs[(kl + 2) * BM + m] = v.z;
                xs[(kl + 3) * BM + m] = v.w;
            }
            // stage cT chunk: 8192 floats. 8 lanes cover one code's 32 k-values.
            #pragma unroll
            for (int q = 0; q < 8; ++q) {
                const int nl = q * 32 + (tid >> 3);
                const int kl = (tid & 7) * 4;
                const float4 v = *reinterpret_cast<const float4*>(
                        cb + (size_t)(nc + nl) * D + kc + kl);
                cs[(kl + 0) * BN + nl] = v.x;
                cs[(kl + 1) * BN + nl] = v.y;
                cs[(kl + 2) * BN + nl] = v.z;
                cs[(kl + 3) * BN + nl] = v.w;
            }
            __syncthreads();

            #pragma unroll 8
            for (int k = 0; k < BK; ++k) {
                const float4 xa = *reinterpret_cast<const float4*>(&xs[k * BM + ty * 8]);
                const float4 xb = *reinterpret_cast<const float4*>(&xs[k * BM + ty * 8 + 4]);
                const float4 ca = *reinterpret_cast<const float4*>(&cs[k * BN + tx * 4]);
                const float4 cc = *reinterpret_cast<const float4*>(&cs[k * BN + 128 + tx * 4]);
                const float xm[8] = {xa.x, xa.y, xa.z, xa.w, xb.x, xb.y, xb.z, xb.w};
                const float cn[8] = {ca.x, ca.y, ca.z, ca.w, cc.x, cc.y, cc.z, cc.w};
                #pragma unroll
                for (int i = 0; i < 8; ++i)
                    #pragma unroll
                    for (int j = 0; j < 8; ++j)
                        acc[i][j] += xm[i] * cn[j];
            }
        }
        // finalize this n-chunk: fold into running argmin
        #pragma unroll
        for (int j = 0; j < 8; ++j) {
            const int nl = (j < 4) ? (tx * 4 + j) : (128 + tx * 4 + (j - 4));
            const int n  = nc + nl;
            const float c2n = c2[n];
            #pragma unroll
            for (int i = 0; i < 8; ++i) {
                const float s = c2n - 2.0f * acc[i][j];
                if (s < runmin[i] || (s == runmin[i] && n < runidx[i])) {
                    runmin[i] = s; runidx[i] = n;
                }
                acc[i][j] = 0.0f;
            }
        }
    }

    // cross-tx reduction (reuse cs; need 4096 floats + 4096 ints = 32 KB exactly)
    __syncthreads();
    float* rv = cs;                                   // rv[t*64 + m]
    int*   ri = reinterpret_cast<int*>(cs + 2048);    // ri[t*64 + m]
    #pragma unroll
    for (int i = 0; i < 8; ++i) {
        rv[tx * 64 + ty * 8 + i] = runmin[i];
        ri[tx * 64 + ty * 8 + i] = runidx[i];
    }
    __syncthreads();
    if (tid < 64) {
        float best = rv[tid];
        int   bidx = ri[tid];
        for (int t = 1; t < 32; ++t) {
            const float v = rv[t * 64 + tid];
            const int  id = ri[t * 64 + tid];
            if (v < best || (v == best && id < bidx)) { best = v; bidx = id; }
        }
        idx_out[m0 + tid] = (float)bidx;
    }
}

// ---------------- kernel 3: gather codes + loss ----------------
// block: 256 threads = 4 rows; 64 lanes per row, float4 per lane.
__global__ void vq_gather_kernel(const float* __restrict__ x, const float* __restrict__ cb,
                                 const float* __restrict__ idxf, float* __restrict__ qout,
                                 float* __restrict__ loss, float scale) {
    const int tid = threadIdx.x;
    const int m   = blockIdx.x * 4 + (tid >> 6);
    const int k   = (tid & 63) * 4;
    const int idx = (int)idxf[m];
    const float4 c  = *reinterpret_cast<const float4*>(cb + (size_t)idx * D + k);
    const float4 xv = *reinterpret_cast<const float4*>(x  + (size_t)m  * D + k);
    *reinterpret_cast<float4*>(qout + (size_t)m * D + k) = c;
    const float dx = c.x - xv.x, dy = c.y - xv.y, dz = c.z - xv.z, dw = c.w - xv.w;
    float s = dx * dx + dy * dy + dz * dz + dw * dw;
    #pragma unroll
    for (int off = 32; off > 0; off >>= 1) s += __shfl_down(s, off, 64);
    if ((tid & 63) == 0) atomicAdd(loss, s * scale);
}

extern "C" void kernel_launch(void* const* d_in, const int* in_sizes, int n_in,
                              void* d_out, int out_size, void* d_ws, size_t ws_size,
                              hipStream_t stream) {
    const float* x  = (const float*)d_in[0];
    const float* cb = (const float*)d_in[1];
    const int M = in_sizes[0] / D;   // 32768
    const int N = in_sizes[1] / D;   // 2048

    float* qout    = (float*)d_out;
    float* idx_out = qout + (size_t)M * D;
    float* loss    = idx_out + M;
    float* c2      = (float*)d_ws;   // N floats of scratch

    hipMemsetAsync(loss, 0, sizeof(float), stream);
    vq_c2_kernel<<<N, 64, 0, stream>>>(cb, c2);
    vq_argmin_kernel<<<M / BM, 256, 0, stream>>>(x, cb, c2, idx_out, N);
    const float scale = 2.0f / (float)((size_t)M * D);  // code_loss + 1.0*embedding_loss
    vq_gather_kernel<<<M / 4, 256, 0, stream>>>(x, cb, idx_out, qout, loss, scale);
}

// Round 2
// 568.904 us; speedup vs baseline: 1.8000x; 1.8000x over previous
//
#include <hip/hip_runtime.h>

#define D  256
#define BM 64
#define BN 256
#define BK 32

// ---------------- kernel 1: codebook squared norms -> ws ----------------
__global__ void vq_c2_kernel(const float* __restrict__ cb, float* __restrict__ c2) {
    const int row  = blockIdx.x;
    const int lane = threadIdx.x;  // 64 threads = 1 wave
    const float4 v = *reinterpret_cast<const float4*>(cb + (size_t)row * D + lane * 4);
    float s = v.x * v.x + v.y * v.y + v.z * v.z + v.w * v.w;
    #pragma unroll
    for (int off = 32; off > 0; off >>= 1) s += __shfl_down(s, off, 64);
    if (lane == 0) c2[row] = s;
}

// ---------------- kernel 2: fused GEMM + argmin ----------------
// block: 256 threads, owns BM=64 rows, iterates all N codes.
// thread micro-tile: 8 rows x 8 cols. tx in [0,32) along n, ty in [0,8) along m.
// score s = c2[n] - 2*dot(x,c); argmin(s) == argmin ||x-c||^2.
// LDS layout is XOR-swizzled: element (k, col) lives at column col ^ ((k>>2 & 7)<<2).
// Writes: lanes sharing col differ in k>>2 -> banks r ^ 4s = exactly 2-way (free).
// Reads: aligned float4 groups permuted by tx ^ kq -> conflict-free, swizzle
// round-trips so the n-index mapping in the finalize step is unchanged.
__global__ __launch_bounds__(256, 2) void vq_argmin_kernel(
        const float* __restrict__ x, const float* __restrict__ cb,
        const float* __restrict__ c2, float* __restrict__ idx_out, int N) {
    __shared__ float xs[BK * BM];   // xT[k][m^swz], 8 KB
    __shared__ float cs[BK * BN];   // cT[k][n^swz], 32 KB

    const int tid = threadIdx.x;
    const int tx  = tid & 31;
    const int ty  = tid >> 5;
    const int m0  = blockIdx.x * BM;
    const float* xg = x + (size_t)m0 * D;

    const int s8 = tid & 7;        // kl/4 for this thread's staging writes
    const int kl = s8 * 4;
    const int swz = s8 << 2;       // column XOR for staging writes

    float runmin[8];
    int   runidx[8];
    #pragma unroll
    for (int i = 0; i < 8; ++i) { runmin[i] = 3.4e38f; runidx[i] = 0; }

    float acc[8][8];
    #pragma unroll
    for (int i = 0; i < 8; ++i)
        #pragma unroll
        for (int j = 0; j < 8; ++j) acc[i][j] = 0.0f;

    for (int nc = 0; nc < N; nc += BN) {
        for (int kc = 0; kc < D; kc += BK) {
            __syncthreads();
            // stage xT chunk: 2048 floats. 8 lanes cover one row's 32 k-values.
            #pragma unroll
            for (int q = 0; q < 2; ++q) {
                const int m  = q * 32 + (tid >> 3);
                const float4 v = *reinterpret_cast<const float4*>(xg + (size_t)m * D + kc + kl);
                const int ms = m ^ swz;
                xs[(kl + 0) * BM + ms] = v.x;
                xs[(kl + 1) * BM + ms] = v.y;
                xs[(kl + 2) * BM + ms] = v.z;
                xs[(kl + 3) * BM + ms] = v.w;
            }
            // stage cT chunk: 8192 floats. 8 lanes cover one code's 32 k-values.
            #pragma unroll
            for (int q = 0; q < 8; ++q) {
                const int nl = q * 32 + (tid >> 3);
                const float4 v = *reinterpret_cast<const float4*>(
                        cb + (size_t)(nc + nl) * D + kc + kl);
                const int ns = nl ^ swz;
                cs[(kl + 0) * BN + ns] = v.x;
                cs[(kl + 1) * BN + ns] = v.y;
                cs[(kl + 2) * BN + ns] = v.z;
                cs[(kl + 3) * BN + ns] = v.w;
            }
            __syncthreads();

            #pragma unroll 8
            for (int k = 0; k < BK; ++k) {
                const int kq = (k >> 2) & 7;
                const float4 xa = *reinterpret_cast<const float4*>(
                        &xs[k * BM + (((2 * ty) ^ kq) << 2)]);
                const float4 xb = *reinterpret_cast<const float4*>(
                        &xs[k * BM + (((2 * ty + 1) ^ kq) << 2)]);
                const float4 ca = *reinterpret_cast<const float4*>(
                        &cs[k * BN + ((tx ^ kq) << 2)]);
                const float4 cc = *reinterpret_cast<const float4*>(
                        &cs[k * BN + 128 + ((tx ^ kq) << 2)]);
                const float xm[8] = {xa.x, xa.y, xa.z, xa.w, xb.x, xb.y, xb.z, xb.w};
                const float cn[8] = {ca.x, ca.y, ca.z, ca.w, cc.x, cc.y, cc.z, cc.w};
                #pragma unroll
                for (int i = 0; i < 8; ++i)
                    #pragma unroll
                    for (int j = 0; j < 8; ++j)
                        acc[i][j] += xm[i] * cn[j];
            }
        }
        // finalize this n-chunk: fold into running argmin
        #pragma unroll
        for (int j = 0; j < 8; ++j) {
            const int nl = (j < 4) ? (tx * 4 + j) : (128 + tx * 4 + (j - 4));
            const int n  = nc + nl;
            const float c2n = c2[n];
            #pragma unroll
            for (int i = 0; i < 8; ++i) {
                const float s = c2n - 2.0f * acc[i][j];
                if (s < runmin[i] || (s == runmin[i] && n < runidx[i])) {
                    runmin[i] = s; runidx[i] = n;
                }
                acc[i][j] = 0.0f;
            }
        }
    }

    // cross-tx reduction (reuse cs; need 4096 floats + 4096 ints = 32 KB exactly)
    __syncthreads();
    float* rv = cs;                                   // rv[t*64 + m]
    int*   ri = reinterpret_cast<int*>(cs + 2048);    // ri[t*64 + m]
    #pragma unroll
    for (int i = 0; i < 8; ++i) {
        rv[tx * 64 + ty * 8 + i] = runmin[i];
        ri[tx * 64 + ty * 8 + i] = runidx[i];
    }
    __syncthreads();
    if (tid < 64) {
        float best = rv[tid];
        int   bidx = ri[tid];
        for (int t = 1; t < 32; ++t) {
            const float v = rv[t * 64 + tid];
            const int  id = ri[t * 64 + tid];
            if (v < best || (v == best && id < bidx)) { best = v; bidx = id; }
        }
        idx_out[m0 + tid] = (float)bidx;
    }
}

// ---------------- kernel 3: gather codes + per-block loss partials ----------------
// block: 256 threads; 16 rows per block over 4 passes; partial sum -> ws.
__global__ void vq_gather_kernel(const float* __restrict__ x, const float* __restrict__ cb,
                                 const float* __restrict__ idxf, float* __restrict__ qout,
                                 float* __restrict__ partial) {
    __shared__ float red[4];
    const int tid = threadIdx.x;
    const int k   = (tid & 63) * 4;
    float s = 0.0f;
    #pragma unroll
    for (int p = 0; p < 4; ++p) {
        const int m   = blockIdx.x * 16 + p * 4 + (tid >> 6);
        const int idx = (int)idxf[m];
        const float4 c  = *reinterpret_cast<const float4*>(cb + (size_t)idx * D + k);
        const float4 xv = *reinterpret_cast<const float4*>(x  + (size_t)m  * D + k);
        *reinterpret_cast<float4*>(qout + (size_t)m * D + k) = c;
        const float dx = c.x - xv.x, dy = c.y - xv.y, dz = c.z - xv.z, dw = c.w - xv.w;
        s += dx * dx + dy * dy + dz * dz + dw * dw;
    }
    #pragma unroll
    for (int off = 32; off > 0; off >>= 1) s += __shfl_down(s, off, 64);
    if ((tid & 63) == 0) red[tid >> 6] = s;
    __syncthreads();
    if (tid == 0) partial[blockIdx.x] = red[0] + red[1] + red[2] + red[3];
}

// ---------------- kernel 4: final loss reduction ----------------
__global__ void vq_reduce_kernel(const float* __restrict__ partial, float* __restrict__ loss,
                                 float scale, int n) {
    __shared__ float red[4];
    const int tid = threadIdx.x;  // 256
    float s = 0.0f;
    for (int i = tid; i < n; i += 256) s += partial[i];
    #pragma unroll
    for (int off = 32; off > 0; off >>= 1) s += __shfl_down(s, off, 64);
    if ((tid & 63) == 0) red[tid >> 6] = s;
    __syncthreads();
    if (tid == 0) loss[0] = (red[0] + red[1] + red[2] + red[3]) * scale;
}

extern "C" void kernel_launch(void* const* d_in, const int* in_sizes, int n_in,
                              void* d_out, int out_size, void* d_ws, size_t ws_size,
                              hipStream_t stream) {
    const float* x  = (const float*)d_in[0];
    const float* cb = (const float*)d_in[1];
    const int M = in_sizes[0] / D;   // 32768
    const int N = in_sizes[1] / D;   // 2048

    float* qout    = (float*)d_out;
    float* idx_out = qout + (size_t)M * D;
    float* loss    = idx_out + M;
    float* c2      = (float*)d_ws;       // N floats
    float* partial = c2 + N;             // M/16 floats

    const int n_gather = M / 16;         // 2048 blocks
    vq_c2_kernel<<<N, 64, 0, stream>>>(cb, c2);
    vq_argmin_kernel<<<M / BM, 256, 0, stream>>>(x, cb, c2, idx_out, N);
    vq_gather_kernel<<<n_gather, 256, 0, stream>>>(x, cb, idx_out, qout, partial);
    const float scale = 2.0f / (float)((size_t)M * D);  // code_loss + 1.0*embedding_loss
    vq_reduce_kernel<<<1, 256, 0, stream>>>(partial, loss, scale, n_gather);
}

// Round 3
// 311.918 us; speedup vs baseline: 3.2831x; 1.8239x over previous
//
#include <hip/hip_runtime.h>

#define D   256
#define BM  64      // rows per block
#define BN  128     // codes per LDS chunk
#define KC  64      // k per LDS chunk (2 MFMA k-steps)

typedef __attribute__((ext_vector_type(8))) short v8s;   // 8 bf16 = 4 VGPR
typedef __attribute__((ext_vector_type(4))) float v4f;
#define MFMA16 __builtin_amdgcn_mfma_f32_16x16x32_bf16

static __device__ inline unsigned short f2bf(float f) {          // RNE
    unsigned u = __float_as_uint(f);
    return (unsigned short)((u + 0x7fffu + ((u >> 16) & 1u)) >> 16);
}
static __device__ inline float bf2f(unsigned short s) {
    return __uint_as_float(((unsigned)s) << 16);
}

// ---------------- kernel 1: split codebook into bf16 hi/lo + exact c2 ----------------
__global__ void vq_prep_cb(const float* __restrict__ cb, float* __restrict__ c2,
                           unsigned short* __restrict__ cbh, unsigned short* __restrict__ cbl) {
    const int row  = blockIdx.x;
    const int lane = threadIdx.x;  // 64
    const float4 v = *reinterpret_cast<const float4*>(cb + (size_t)row * D + lane * 4);
    float s = v.x * v.x + v.y * v.y + v.z * v.z + v.w * v.w;
    ushort4 h, l;
    h.x = f2bf(v.x); l.x = f2bf(v.x - bf2f(h.x));
    h.y = f2bf(v.y); l.y = f2bf(v.y - bf2f(h.y));
    h.z = f2bf(v.z); l.z = f2bf(v.z - bf2f(h.z));
    h.w = f2bf(v.w); l.w = f2bf(v.w - bf2f(h.w));
    *reinterpret_cast<ushort4*>(cbh + (size_t)row * D + lane * 4) = h;
    *reinterpret_cast<ushort4*>(cbl + (size_t)row * D + lane * 4) = l;
    #pragma unroll
    for (int off = 32; off > 0; off >>= 1) s += __shfl_down(s, off, 64);
    if (lane == 0) c2[row] = s;
}

// ---------------- kernel 2: MFMA argmin ----------------
// score s = c2[n] - 2*x.c ; x.c via split-bf16 3-pass (xh*ch + xl*ch + xh*cl).
// 4 waves: mg = w>>1 selects 32-row half (2 m-tiles resident in regs),
//          ng = w&1  selects 64-code half of each BN chunk (4 n-tiles).
// LDS c-chunks stored seg-major: [seg 0..7][n 0..127][8 bf16] per hi/lo array.
__global__ __launch_bounds__(256, 2) void vq_argmin_mfma(
        const float* __restrict__ x, const unsigned short* __restrict__ cbh,
        const unsigned short* __restrict__ cbl, const float* __restrict__ c2,
        float* __restrict__ idx_out, int N) {
    __shared__ unsigned short lds_h[8 * BN * 8];   // 16 KB
    __shared__ unsigned short lds_l[8 * BN * 8];   // 16 KB
    __shared__ float red_v[64 * 32];               // 8 KB
    __shared__ int   red_i[64 * 32];               // 8 KB

    const int tid  = threadIdx.x;
    const int w    = tid >> 6;
    const int lane = tid & 63;
    const int col  = lane & 15;     // MFMA col / A-row selector
    const int quad = lane >> 4;     // k-block selector
    const int mg   = w >> 1;
    const int ng   = w & 1;
    const int m0   = blockIdx.x * BM;

    // ---- load A-frags: rows m0 + mg*32 + mt*16 + col, full K, hi+lo (128 VGPR) ----
    v8s xh[2][8], xl[2][8];
    #pragma unroll
    for (int mt = 0; mt < 2; ++mt) {
        const float* xr = x + (size_t)(m0 + mg * 32 + mt * 16 + col) * D;
        #pragma unroll
        for (int ks = 0; ks < 8; ++ks) {
            const int kb = ks * 32 + quad * 8;
            const float4 f0 = *reinterpret_cast<const float4*>(xr + kb);
            const float4 f1 = *reinterpret_cast<const float4*>(xr + kb + 4);
            float f[8] = {f0.x, f0.y, f0.z, f0.w, f1.x, f1.y, f1.z, f1.w};
            v8s h, l;
            #pragma unroll
            for (int j = 0; j < 8; ++j) {
                unsigned short hb = f2bf(f[j]);
                h[j] = (short)hb;
                l[j] = (short)f2bf(f[j] - bf2f(hb));
            }
            xh[mt][ks] = h; xl[mt][ks] = l;
        }
    }

    float runmin[2][4];
    int   runidx[2][4];
    #pragma unroll
    for (int mt = 0; mt < 2; ++mt)
        #pragma unroll
        for (int r = 0; r < 4; ++r) { runmin[mt][r] = 3.4e38f; runidx[mt][r] = 0; }

    v4f acc[4][2];
    #pragma unroll
    for (int nt = 0; nt < 4; ++nt)
        #pragma unroll
        for (int mt = 0; mt < 2; ++mt) acc[nt][mt] = 0.0f;

    for (int nc = 0; nc < N; nc += BN) {
        for (int kc = 0; kc < D; kc += KC) {
            __syncthreads();
            // stage hi+lo chunk: [BN rows] x [KC k] -> seg-major LDS.
            // lane covers (n = lin>>3, seg = lin&7): global 8 rows x 128 B contiguous.
            #pragma unroll
            for (int i = 0; i < 4; ++i) {
                const int lin = i * 256 + tid;
                const int n   = lin >> 3;
                const int seg = lin & 7;
                const size_t goff = (size_t)(nc + n) * D + kc + seg * 8;
                const int    loff = seg * (BN * 8) + n * 8;
                *reinterpret_cast<v8s*>(&lds_h[loff]) =
                    *reinterpret_cast<const v8s*>(cbh + goff);
                *reinterpret_cast<v8s*>(&lds_l[loff]) =
                    *reinterpret_cast<const v8s*>(cbl + goff);
            }
            __syncthreads();

            #pragma unroll
            for (int ksk = 0; ksk < 2; ++ksk) {
                const int ks  = (kc / 32) + ksk;          // global k-step 0..7
                const int seg = ksk * 4 + quad;
                #pragma unroll
                for (int nt = 0; nt < 4; ++nt) {
                    const int nl = ng * 64 + nt * 16 + col;   // row within chunk
                    const int lo = seg * (BN * 8) + nl * 8;
                    const v8s ch = *reinterpret_cast<const v8s*>(&lds_h[lo]);
                    const v8s cl = *reinterpret_cast<const v8s*>(&lds_l[lo]);
                    #pragma unroll
                    for (int mt = 0; mt < 2; ++mt) {
                        acc[nt][mt] = MFMA16(xh[mt][ks], ch, acc[nt][mt], 0, 0, 0);
                        acc[nt][mt] = MFMA16(xl[mt][ks], ch, acc[nt][mt], 0, 0, 0);
                        acc[nt][mt] = MFMA16(xh[mt][ks], cl, acc[nt][mt], 0, 0, 0);
                    }
                }
            }
        }
        // finalize chunk: fold scores into running argmin
        #pragma unroll
        for (int nt = 0; nt < 4; ++nt) {
            const int n   = nc + ng * 64 + nt * 16 + col;
            const float c2n = c2[n];
            #pragma unroll
            for (int mt = 0; mt < 2; ++mt) {
                #pragma unroll
                for (int r = 0; r < 4; ++r) {
                    const float s = c2n - 2.0f * acc[nt][mt][r];
                    if (s < runmin[mt][r]) { runmin[mt][r] = s; runidx[mt][r] = n; }
                }
                acc[nt][mt] = 0.0f;
            }
        }
    }

    // ---- merge: row = mg*32 + mt*16 + quad*4 + r ; slot = ng*16 + col ----
    __syncthreads();
    #pragma unroll
    for (int mt = 0; mt < 2; ++mt)
        #pragma unroll
        for (int r = 0; r < 4; ++r) {
            const int row = mg * 32 + mt * 16 + quad * 4 + r;
            red_v[row * 32 + ng * 16 + col] = runmin[mt][r];
            red_i[row * 32 + ng * 16 + col] = runidx[mt][r];
        }
    __syncthreads();
    if (tid < 64) {
        float best = red_v[tid * 32];
        int   bidx = red_i[tid * 32];
        for (int t = 1; t < 32; ++t) {
            const float v = red_v[tid * 32 + t];
            const int  id = red_i[tid * 32 + t];
            if (v < best || (v == best && id < bidx)) { best = v; bidx = id; }
        }
        idx_out[m0 + tid] = (float)bidx;
    }
}

// ---------------- kernel 3: gather codes + per-block loss partials ----------------
__global__ void vq_gather_kernel(const float* __restrict__ x, const float* __restrict__ cb,
                                 const float* __restrict__ idxf, float* __restrict__ qout,
                                 float* __restrict__ partial) {
    __shared__ float red[4];
    const int tid = threadIdx.x;
    const int k   = (tid & 63) * 4;
    float s = 0.0f;
    #pragma unroll
    for (int p = 0; p < 4; ++p) {
        const int m   = blockIdx.x * 16 + p * 4 + (tid >> 6);
        const int idx = (int)idxf[m];
        const float4 c  = *reinterpret_cast<const float4*>(cb + (size_t)idx * D + k);
        const float4 xv = *reinterpret_cast<const float4*>(x  + (size_t)m  * D + k);
        *reinterpret_cast<float4*>(qout + (size_t)m * D + k) = c;
        const float dx = c.x - xv.x, dy = c.y - xv.y, dz = c.z - xv.z, dw = c.w - xv.w;
        s += dx * dx + dy * dy + dz * dz + dw * dw;
    }
    #pragma unroll
    for (int off = 32; off > 0; off >>= 1) s += __shfl_down(s, off, 64);
    if ((tid & 63) == 0) red[tid >> 6] = s;
    __syncthreads();
    if (tid == 0) partial[blockIdx.x] = red[0] + red[1] + red[2] + red[3];
}

// ---------------- kernel 4: final loss reduction ----------------
__global__ void vq_reduce_kernel(const float* __restrict__ partial, float* __restrict__ loss,
                                 float scale, int n) {
    __shared__ float red[4];
    const int tid = threadIdx.x;
    float s = 0.0f;
    for (int i = tid; i < n; i += 256) s += partial[i];
    #pragma unroll
    for (int off = 32; off > 0; off >>= 1) s += __shfl_down(s, off, 64);
    if ((tid & 63) == 0) red[tid >> 6] = s;
    __syncthreads();
    if (tid == 0) loss[0] = (red[0] + red[1] + red[2] + red[3]) * scale;
}

extern "C" void kernel_launch(void* const* d_in, const int* in_sizes, int n_in,
                              void* d_out, int out_size, void* d_ws, size_t ws_size,
                              hipStream_t stream) {
    const float* x  = (const float*)d_in[0];
    const float* cb = (const float*)d_in[1];
    const int M = in_sizes[0] / D;   // 32768
    const int N = in_sizes[1] / D;   // 2048

    float* qout    = (float*)d_out;
    float* idx_out = qout + (size_t)M * D;
    float* loss    = idx_out + M;

    // ws layout (bytes): c2 [0,8K) | cbh [8K, 8K+1M) | cbl | partial
    char* wsb = (char*)d_ws;
    float*          c2      = (float*)wsb;
    unsigned short* cbh     = (unsigned short*)(wsb + 8192);
    unsigned short* cbl     = cbh + (size_t)N * D;
    float*          partial = (float*)(wsb + 8192 + 2 * (size_t)N * D * sizeof(unsigned short));

    vq_prep_cb<<<N, 64, 0, stream>>>(cb, c2, cbh, cbl);
    vq_argmin_mfma<<<M / BM, 256, 0, stream>>>(x, cbh, cbl, c2, idx_out, N);
    const int n_gather = M / 16;
    vq_gather_kernel<<<n_gather, 256, 0, stream>>>(x, cb, idx_out, qout, partial);
    const float scale = 2.0f / (float)((size_t)M * D);
    vq_reduce_kernel<<<1, 256, 0, stream>>>(partial, loss, scale, n_gather);
}

// Round 4
// 249.139 us; speedup vs baseline: 4.1103x; 1.2520x over previous
//
#include <hip/hip_runtime.h>

#define D   256
#define BM  64      // rows per block
#define BN  128     // codes per LDS chunk
#define KC  128     // k per LDS chunk (4 MFMA k-steps)

typedef __attribute__((ext_vector_type(8))) short v8s;   // 8 bf16 = 4 VGPR
typedef __attribute__((ext_vector_type(4))) float v4f;
#define MFMA16 __builtin_amdgcn_mfma_f32_16x16x32_bf16

static __device__ inline unsigned short f2bf(float f) {          // RNE
    unsigned u = __float_as_uint(f);
    return (unsigned short)((u + 0x7fffu + ((u >> 16) & 1u)) >> 16);
}
static __device__ inline float bf2f(unsigned short s) {
    return __uint_as_float(((unsigned)s) << 16);
}

// ---------------- kernel 1: split codebook into bf16 hi/lo + exact c2 ----------------
__global__ void vq_prep_cb(const float* __restrict__ cb, float* __restrict__ c2,
                           unsigned short* __restrict__ cbh, unsigned short* __restrict__ cbl) {
    const int row  = blockIdx.x;
    const int lane = threadIdx.x;  // 64
    const float4 v = *reinterpret_cast<const float4*>(cb + (size_t)row * D + lane * 4);
    float s = v.x * v.x + v.y * v.y + v.z * v.z + v.w * v.w;
    ushort4 h, l;
    h.x = f2bf(v.x); l.x = f2bf(v.x - bf2f(h.x));
    h.y = f2bf(v.y); l.y = f2bf(v.y - bf2f(h.y));
    h.z = f2bf(v.z); l.z = f2bf(v.z - bf2f(h.z));
    h.w = f2bf(v.w); l.w = f2bf(v.w - bf2f(h.w));
    *reinterpret_cast<ushort4*>(cbh + (size_t)row * D + lane * 4) = h;
    *reinterpret_cast<ushort4*>(cbl + (size_t)row * D + lane * 4) = l;
    #pragma unroll
    for (int off = 32; off > 0; off >>= 1) s += __shfl_down(s, off, 64);
    if (lane == 0) c2[row] = s;
}

// ---------------- kernel 2: MFMA argmin + fused gather/loss ----------------
// score s = c2[n] - 2*x.c ; x.c via split-bf16 3-pass (xh*ch + xl*ch + xh*cl).
// LDS granules (16 B) placed at p = seg*BN + (n ^ (seg&7)):
//   writes: octet has n const, seg 0..7 -> groups (n^seg)&7 all distinct (conflict-free)
//   reads:  octet has seg const, col 0..7 -> groups (col^seg)&7 all distinct (conflict-free)
__global__ __launch_bounds__(256, 2) void vq_argmin_mfma(
        const float* __restrict__ x, const float* __restrict__ cb,
        const unsigned short* __restrict__ cbh, const unsigned short* __restrict__ cbl,
        const float* __restrict__ c2, float* __restrict__ idx_out,
        float* __restrict__ qout, float* __restrict__ partial, int N) {
    __shared__ unsigned short lds_h[16 * BN * 8];  // 32 KB
    __shared__ unsigned short lds_l[16 * BN * 8];  // 32 KB
    __shared__ float red_v[64 * 32];               // 8 KB
    __shared__ int   red_i[64 * 32];               // 8 KB  (total 80 KB -> 2 blocks/CU)

    const int tid  = threadIdx.x;
    const int w    = tid >> 6;
    const int lane = tid & 63;
    const int col  = lane & 15;     // MFMA col / A-row selector
    const int quad = lane >> 4;     // k-granule selector
    const int mg   = w >> 1;
    const int ng   = w & 1;
    const int m0   = blockIdx.x * BM;

    // ---- load A-frags: rows m0 + mg*32 + mt*16 + col, full K, hi+lo (128 VGPR) ----
    v8s xh[2][8], xl[2][8];
    #pragma unroll
    for (int mt = 0; mt < 2; ++mt) {
        const float* xr = x + (size_t)(m0 + mg * 32 + mt * 16 + col) * D;
        #pragma unroll
        for (int ks = 0; ks < 8; ++ks) {
            const int kb = ks * 32 + quad * 8;
            const float4 f0 = *reinterpret_cast<const float4*>(xr + kb);
            const float4 f1 = *reinterpret_cast<const float4*>(xr + kb + 4);
            float f[8] = {f0.x, f0.y, f0.z, f0.w, f1.x, f1.y, f1.z, f1.w};
            v8s h, l;
            #pragma unroll
            for (int j = 0; j < 8; ++j) {
                unsigned short hb = f2bf(f[j]);
                h[j] = (short)hb;
                l[j] = (short)f2bf(f[j] - bf2f(hb));
            }
            xh[mt][ks] = h; xl[mt][ks] = l;
        }
    }

    float runmin[2][4];
    int   runidx[2][4];
    #pragma unroll
    for (int mt = 0; mt < 2; ++mt)
        #pragma unroll
        for (int r = 0; r < 4; ++r) { runmin[mt][r] = 3.4e38f; runidx[mt][r] = 0; }

    v4f acc[4][2];
    #pragma unroll
    for (int nt = 0; nt < 4; ++nt)
        #pragma unroll
        for (int mt = 0; mt < 2; ++mt) acc[nt][mt] = 0.0f;

    for (int nc = 0; nc < N; nc += BN) {
        for (int kc = 0; kc < D; kc += KC) {
            __syncthreads();
            // stage hi+lo chunk: 2048 granules per array, 8 per thread.
            #pragma unroll
            for (int i = 0; i < 8; ++i) {
                const int lin = i * 256 + tid;
                const int n   = lin >> 4;           // 0..127
                const int seg = lin & 15;           // 0..15
                const size_t goff = (size_t)(nc + n) * D + kc + seg * 8;
                const int    p    = seg * BN + (n ^ (seg & 7));
                *reinterpret_cast<v8s*>(&lds_h[p * 8]) =
                    *reinterpret_cast<const v8s*>(cbh + goff);
                *reinterpret_cast<v8s*>(&lds_l[p * 8]) =
                    *reinterpret_cast<const v8s*>(cbl + goff);
            }
            __syncthreads();

            #pragma unroll
            for (int ksk = 0; ksk < 4; ++ksk) {
                const int ks  = (kc >> 5) + ksk;    // global k-step 0..7
                const int seg = ksk * 4 + quad;     // 0..15
                const int sx  = seg & 7;
                #pragma unroll
                for (int nt = 0; nt < 4; ++nt) {
                    const int p = seg * BN + ng * 64 + nt * 16 + (col ^ sx);
                    const v8s ch = *reinterpret_cast<const v8s*>(&lds_h[p * 8]);
                    const v8s cl = *reinterpret_cast<const v8s*>(&lds_l[p * 8]);
                    #pragma unroll
                    for (int mt = 0; mt < 2; ++mt) {
                        acc[nt][mt] = MFMA16(xh[mt][ks], ch, acc[nt][mt], 0, 0, 0);
                        acc[nt][mt] = MFMA16(xl[mt][ks], ch, acc[nt][mt], 0, 0, 0);
                        acc[nt][mt] = MFMA16(xh[mt][ks], cl, acc[nt][mt], 0, 0, 0);
                    }
                }
            }
        }
        // finalize chunk: fold scores into running argmin
        #pragma unroll
        for (int nt = 0; nt < 4; ++nt) {
            const int n   = nc + ng * 64 + nt * 16 + col;
            const float c2n = c2[n];
            #pragma unroll
            for (int mt = 0; mt < 2; ++mt) {
                #pragma unroll
                for (int r = 0; r < 4; ++r) {
                    const float s = c2n - 2.0f * acc[nt][mt][r];
                    if (s < runmin[mt][r]) { runmin[mt][r] = s; runidx[mt][r] = n; }
                }
                acc[nt][mt] = 0.0f;
            }
        }
    }

    // ---- merge: row = mg*32 + mt*16 + quad*4 + r ; slot = ng*16 + col (swizzled) ----
    __syncthreads();
    #pragma unroll
    for (int mt = 0; mt < 2; ++mt)
        #pragma unroll
        for (int r = 0; r < 4; ++r) {
            const int row  = mg * 32 + mt * 16 + quad * 4 + r;
            const int slot = (ng * 16 + col) ^ (row & 31);
            red_v[row * 32 + slot] = runmin[mt][r];
            red_i[row * 32 + slot] = runidx[mt][r];
        }
    __syncthreads();
    float best = 3.4e38f;
    int   bidx = 0;
    if (tid < 64) {
        #pragma unroll 4
        for (int t = 0; t < 32; ++t) {
            const int  sl = t ^ (tid & 31);
            const float v = red_v[tid * 32 + sl];
            const int  id = red_i[tid * 32 + sl];
            if (v < best || (v == best && id < bidx)) { best = v; bidx = id; }
        }
        idx_out[m0 + tid] = (float)bidx;
    }
    __syncthreads();
    int* idx_sh = reinterpret_cast<int*>(red_v);
    if (tid < 64) idx_sh[tid] = bidx;
    __syncthreads();

    // ---- fused gather + loss over this block's 64 rows (x tile is L2-hot) ----
    const float* xg2 = x + (size_t)m0 * D;
    float s = 0.0f;
    #pragma unroll
    for (int i = 0; i < 16; ++i) {
        const int g   = i * 256 + tid;      // float4-granule, 4096 total
        const int row = g >> 6;
        const int k4  = (g & 63) * 4;
        const int idx = idx_sh[row];
        const float4 c  = *reinterpret_cast<const float4*>(cb  + (size_t)idx * D + k4);
        const float4 xv = *reinterpret_cast<const float4*>(xg2 + (size_t)row * D + k4);
        *reinterpret_cast<float4*>(qout + (size_t)(m0 + row) * D + k4) = c;
        const float dx = c.x - xv.x, dy = c.y - xv.y, dz = c.z - xv.z, dw = c.w - xv.w;
        s += dx * dx + dy * dy + dz * dz + dw * dw;
    }
    #pragma unroll
    for (int off = 32; off > 0; off >>= 1) s += __shfl_down(s, off, 64);
    float* wsum = reinterpret_cast<float*>(red_i);
    if ((tid & 63) == 0) wsum[tid >> 6] = s;
    __syncthreads();
    if (tid == 0) partial[blockIdx.x] = wsum[0] + wsum[1] + wsum[2] + wsum[3];
}

// ---------------- kernel 3: final loss reduction ----------------
__global__ void vq_reduce_kernel(const float* __restrict__ partial, float* __restrict__ loss,
                                 float scale, int n) {
    __shared__ float red[4];
    const int tid = threadIdx.x;
    float s = 0.0f;
    for (int i = tid; i < n; i += 256) s += partial[i];
    #pragma unroll
    for (int off = 32; off > 0; off >>= 1) s += __shfl_down(s, off, 64);
    if ((tid & 63) == 0) red[tid >> 6] = s;
    __syncthreads();
    if (tid == 0) loss[0] = (red[0] + red[1] + red[2] + red[3]) * scale;
}

extern "C" void kernel_launch(void* const* d_in, const int* in_sizes, int n_in,
                              void* d_out, int out_size, void* d_ws, size_t ws_size,
                              hipStream_t stream) {
    const float* x  = (const float*)d_in[0];
    const float* cb = (const float*)d_in[1];
    const int M = in_sizes[0] / D;   // 32768
    const int N = in_sizes[1] / D;   // 2048

    float* qout    = (float*)d_out;
    float* idx_out = qout + (size_t)M * D;
    float* loss    = idx_out + M;

    // ws layout (bytes): c2 [0,8K) | cbh [8K, +1M) | cbl [+1M) | partial
    char* wsb = (char*)d_ws;
    float*          c2      = (float*)wsb;
    unsigned short* cbh     = (unsigned short*)(wsb + 8192);
    unsigned short* cbl     = cbh + (size_t)N * D;
    float*          partial = (float*)(wsb + 8192 + 2 * (size_t)N * D * sizeof(unsigned short));

    vq_prep_cb<<<N, 64, 0, stream>>>(cb, c2, cbh, cbl);
    vq_argmin_mfma<<<M / BM, 256, 0, stream>>>(x, cb, cbh, cbl, c2, idx_out, qout, partial, N);
    const float scale = 2.0f / (float)((size_t)M * D);
    vq_reduce_kernel<<<1, 256, 0, stream>>>(partial, loss, scale, M / BM);
}